// Round 28
// baseline (174.599 us; speedup 1.0000x reference)
//
#include <hip/hip_runtime.h>
#include <hip/hip_bf16.h>
#include <stdint.h>

typedef float          f32x4  __attribute__((ext_vector_type(4)));
typedef float          f32x16 __attribute__((ext_vector_type(16)));
typedef short          s16x8  __attribute__((ext_vector_type(8)));
typedef unsigned short u16;
typedef u16            u16x4 __attribute__((ext_vector_type(4)));
typedef u16            u16x8 __attribute__((ext_vector_type(8)));
typedef unsigned int   u32;
typedef u32            u32x4 __attribute__((ext_vector_type(4)));

#define DMODEL 1024
#define NH     16
#define DH     64
#define SEQ    2048
#define BATCH  4
#define NROW   (BATCH*SEQ)   // 8192
#define N3     (3*DMODEL)    // 3072

#define KEXP 0.1803368801f   // (1/sqrt(64)) * log2(e), folded into Q

__device__ __forceinline__ u16 f2bf(float f) {
    __hip_bfloat16 h = __float2bfloat16(f);   // RNE conversion
    u16 u;
    __builtin_memcpy(&u, &h, 2);
    return u;
}

typedef const __attribute__((address_space(1))) void* gas_t;
typedef __attribute__((address_space(3))) void* las_t;
__device__ __forceinline__ void async16(void* lds, const void* g) {
    __builtin_amdgcn_global_load_lds((gas_t)g, (las_t)lds, 16, 0, 0);
}

__device__ __forceinline__ f32x4 mfma16(s16x8 a, s16x8 b, f32x4 c) {
    return __builtin_amdgcn_mfma_f32_16x16x32_bf16(a, b, c, 0, 0, 0);
}
__device__ __forceinline__ f32x16 mfma32(s16x8 a, s16x8 b, f32x16 c) {
    return __builtin_amdgcn_mfma_f32_32x32x16_bf16(a, b, c, 0, 0, 0);
}

#define SWZ(row) (((row) & 7) ^ ((((row) >> 3) & 3) << 1))

// ---------------------------------------------------------------- fused casts
// blocks [0, 4096): x -> bf16 ; blocks [4096, 4864): W [k][n] -> Wt bf16 [n][k]
__global__ __launch_bounds__(256)
void cast_fused_kernel(const float* __restrict__ xin, u16* __restrict__ xb,
                       const float* __restrict__ W,  u16* __restrict__ Wt)
{
    __shared__ u16 T[64][72];          // used by the W branch only
    const int t = threadIdx.x;
    if (blockIdx.x < 4096) {
        const int i = blockIdx.x * 256 + t;
        const f32x4* p = (const f32x4*)xin;
        f32x4 a = p[2*i], b = p[2*i+1];
        u16x8 o;
        o[0]=f2bf(a[0]); o[1]=f2bf(a[1]); o[2]=f2bf(a[2]); o[3]=f2bf(a[3]);
        o[4]=f2bf(b[0]); o[5]=f2bf(b[1]); o[6]=f2bf(b[2]); o[7]=f2bf(b[3]);
        ((u16x8*)xb)[i] = o;
        return;
    }
    const int bid2 = blockIdx.x - 4096;           // 0..767
    const int n0 = (bid2 % (N3/64)) * 64;
    const int k0 = (bid2 / (N3/64)) * 64;
    {
        const int c4 = t & 15, rr = t >> 4;
        #pragma unroll
        for (int ri = 0; ri < 4; ++ri) {
            const int r = ri*16 + rr;
            f32x4 v = *(const f32x4*)&W[(size_t)(k0 + r) * N3 + n0 + c4*4];
            #pragma unroll
            for (int e = 0; e < 4; ++e) T[r][c4*4+e] = f2bf(v[e]);
        }
    }
    __syncthreads();
    {
        const int nr = t >> 2, kq = t & 3;
        #pragma unroll
        for (int pp = 0; pp < 2; ++pp) {
            const int kb = kq + pp*4;
            u16x8 o;
            #pragma unroll
            for (int e = 0; e < 8; ++e) o[e] = T[kb*8+e][nr];
            *(u16x8*)&Wt[(size_t)(n0 + nr) * DMODEL + k0 + kb*8] = o;
        }
    }
}

// ---------------------------------------------------------------- QKV GEMM (bf16 MFMA)
// C[8192,3072] = xb @ Wt^T + bias; writes Qb (pre-scaled by KEXP) / Kb [b,h,s,d], Vt [b,h,d,s]
// r28: 2-phase double-buffered K-loop (same T3-minimum pipeline as attn r10):
// prefetch K-step k+1 while computing k; one vmcnt(0)+barrier per step.
__global__ __launch_bounds__(256)
void qkv_mfma_kernel(const u16* __restrict__ xb, const u16* __restrict__ Wt,
                     const float* __restrict__ bias,
                     u16* __restrict__ Qb, u16* __restrict__ Kb, u16* __restrict__ Vt)
{
    __shared__ u16 As[2][128*32];   // [dbuf][m][k] linear
    __shared__ u16 Bs[2][128*32];   // [dbuf][n][k] linear (B^T)

    const int tid  = threadIdx.x;
    const int lane = tid & 63;
    const int w    = tid >> 6;
    const int wm   = w >> 1, wn = w & 1;
    const int n0   = blockIdx.x * 128;
    const int m0   = blockIdx.y * 128;

    const int srow = w*32 + (lane >> 2);
    const int scol = (lane & 3) * 8;
    const int ado0 = (w*2+0)*512 + lane*8;
    const int ado1 = (w*2+1)*512 + lane*8;
    const u16* ag0 = &xb[(size_t)(m0 + srow)      * DMODEL + scol];
    const u16* ag1 = &xb[(size_t)(m0 + srow + 16) * DMODEL + scol];
    const u16* bg0 = &Wt[(size_t)(n0 + srow)      * DMODEL + scol];
    const u16* bg1 = &Wt[(size_t)(n0 + srow + 16) * DMODEL + scol];

    f32x4 acc[4][4];
    #pragma unroll
    for (int i = 0; i < 4; ++i)
        #pragma unroll
        for (int j = 0; j < 4; ++j)
            acc[i][j] = (f32x4){0.f, 0.f, 0.f, 0.f};

    const int arow = (wm*64 + (lane&15))*32 + (lane>>4)*8;   // + mi*512
    const int brow = (wn*64 + (lane&15))*32 + (lane>>4)*8;   // + ni*512

#define GSTAGE(buf, k0) do {                        \
        async16(&As[buf][ado0], ag0 + (k0));        \
        async16(&As[buf][ado1], ag1 + (k0));        \
        async16(&Bs[buf][ado0], bg0 + (k0));        \
        async16(&Bs[buf][ado1], bg1 + (k0));        \
    } while (0)

#define GCOMPUTE(buf) do {                                                   \
        s16x8 af[4], bf[4];                                                  \
        _Pragma("unroll")                                                    \
        for (int mi = 0; mi < 4; ++mi)                                       \
            af[mi] = *(const s16x8*)&As[buf][arow + mi*512];                 \
        _Pragma("unroll")                                                    \
        for (int ni = 0; ni < 4; ++ni)                                       \
            bf[ni] = *(const s16x8*)&Bs[buf][brow + ni*512];                 \
        _Pragma("unroll")                                                    \
        for (int mi = 0; mi < 4; ++mi)                                       \
            _Pragma("unroll")                                                \
            for (int ni = 0; ni < 4; ++ni)                                   \
                acc[mi][ni] = mfma16(af[mi], bf[ni], acc[mi][ni]);           \
    } while (0)

    // prologue: stage K-step 0 into buf 0
    GSTAGE(0, 0);
    asm volatile("s_waitcnt vmcnt(0)" ::: "memory");
    __builtin_amdgcn_s_barrier();

    for (int k0 = 0; k0 < DMODEL; k0 += 64) {
        GSTAGE(1, k0 + 32);                       // k0+32 <= 992 always
        GCOMPUTE(0);
        asm volatile("s_waitcnt vmcnt(0)" ::: "memory");
        __builtin_amdgcn_s_barrier();
        if (k0 + 64 < DMODEL) GSTAGE(0, k0 + 64);
        GCOMPUTE(1);
        asm volatile("s_waitcnt vmcnt(0)" ::: "memory");
        __builtin_amdgcn_s_barrier();
    }

#undef GSTAGE
#undef GCOMPUTE

    const int part  = n0 >> 10;                // 0=Q 1=K 2=V
    const int col_l = lane & 15;
    const int h     = ((n0 & 1023) >> 6) + wn;
    float bv[4];
    #pragma unroll
    for (int ni = 0; ni < 4; ++ni) bv[ni] = bias[n0 + wn*64 + ni*16 + col_l];

    const int rbase = m0 + wm*64 + (lane>>4)*4;
    u16* qk = (part == 0) ? Qb : Kb;
    #pragma unroll
    for (int mi = 0; mi < 4; ++mi) {
        const int r0 = rbase + mi*16;
        const int b  = r0 >> 11;
        const int s  = r0 & 2047;
        #pragma unroll
        for (int ni = 0; ni < 4; ++ni) {
            const int d = ni*16 + col_l;
            if (part < 2) {
                u16* base = &qk[(((size_t)b*NH + h)*SEQ + s)*DH + d];
                #pragma unroll
                for (int j = 0; j < 4; ++j) {
                    float v = acc[mi][ni][j] + bv[ni];
                    if (part == 0) v *= KEXP;      // fold softmax scale into Q
                    base[(size_t)j*DH] = f2bf(v);
                }
            } else {
                u16x4 o;
                #pragma unroll
                for (int j = 0; j < 4; ++j) o[j] = f2bf(acc[mi][ni][j] + bv[ni]);
                *(u16x4*)&Vt[(((size_t)b*NH + h)*DH + d)*SEQ + s] = o;
            }
        }
    }
}

// ---------------------------------------------------------------- attention (bf16 MFMA, 32x32)
// r19-proven geometry (102.8us, VGPR=88-96): block = (b,h) x 256-query tile;
// 8 waves x 32 q-rows; grid = (bh, qtile) -> XCD = bh%8, per-XCD K/V = 4MB = L2
// (r27: FETCH 139->41MB, verified). 2 blocks/CU. KV round = 128 keys.
// SWAPPED QK^T via 32x32x16; P register-resident. Compute-bound at this
// structure (r27: FETCH -3.4x with zero dur change).
__global__ __launch_bounds__(512)
void attn_mfma_kernel(const u16* __restrict__ Qb, const u16* __restrict__ Kb,
                      const u16* __restrict__ Vt, float* __restrict__ out)
{
    __shared__ u16 Ks[2][2][64*64];   // [dbuf][sub][key][d], swizzled via source
    __shared__ u16 Vs[2][2][64*64];   // [dbuf][sub][d][key], swizzled via source

    const int tid  = threadIdx.x;
    const int lane = tid & 63;
    const int w    = tid >> 6;            // 0..7
    const int bh   = blockIdx.x;          // fast dim -> XCD = bh % 8
    const int q0   = blockIdx.y * 256;
    const size_t qkoff = (size_t)bh * SEQ * DH;

    const int l5  = lane >> 5;       // 0..1
    const int l31 = lane & 31;       // 0..31

    // Q fragments (B-operand): col=q=l31, k = dop*16 + l5*8 + e
    s16x8 qf[4];
    {
        const u16* qp = &Qb[qkoff + (size_t)(q0 + w*32 + l31)*DH];
        #pragma unroll
        for (int dop = 0; dop < 4; ++dop)
            qf[dop] = *(const s16x8*)(qp + dop*16 + l5*8);
    }

    // staging: 512 threads x 16B = 8KB = one 64-key subtile per issue
    const int skey = tid >> 3;            // 0..63 (row within subtile)
    const int sg   = tid & 7;             // granule within 128B row
    const int gsw8 = (sg ^ SWZ(skey)) * 8;
    const int sdo  = tid * 8;             // linear LDS dest (u16 units)
    const u16* kgb = &Kb[qkoff + (size_t)skey * DH + gsw8];
    const u16* vgb = &Vt[((size_t)bh * DH + skey) * SEQ + gsw8];

    f32x16 oacc[2];
    #pragma unroll
    for (int i = 0; i < 16; ++i) { oacc[0][i] = 0.f; oacc[1][i] = 0.f; }
    float psum = 0.f;

#define STAGE(buf, kb2) do {                                          \
        const size_t _o = (size_t)(kb2) * 128;                        \
        async16(&Ks[buf][0][sdo], kgb + (_o     ) * DH);              \
        async16(&Ks[buf][1][sdo], kgb + (_o + 64) * DH);              \
        async16(&Vs[buf][0][sdo], vgb + _o);                          \
        async16(&Vs[buf][1][sdo], vgb + _o + 64);                     \
    } while (0)

#define COMPUTE(buf, sub) do {                                                   \
        const char* ksb = (const char*)Ks[buf][sub];                             \
        const char* vsb = (const char*)Vs[buf][sub];                             \
        f32x16 sacc[2];                                                          \
        _Pragma("unroll")                                                        \
        for (int i = 0; i < 16; ++i) { sacc[0][i] = 0.f; sacc[1][i] = 0.f; }     \
        __builtin_amdgcn_s_setprio(1);                                           \
        _Pragma("unroll")                                                        \
        for (int dop = 0; dop < 4; ++dop) {                                      \
            _Pragma("unroll")                                                    \
            for (int kb32 = 0; kb32 < 2; ++kb32) {                               \
                const int rowK = kb32*32 + l31;                                  \
                const int gK   = 2*dop + l5;                                     \
                s16x8 kf = *(const s16x8*)(ksb + rowK*128                        \
                                           + ((gK ^ SWZ(rowK)) << 4));           \
                sacc[kb32] = mfma32(kf, qf[dop], sacc[kb32]);                    \
            }                                                                    \
        }                                                                        \
        __builtin_amdgcn_s_setprio(0);                                           \
        /* p = 2^s; pack bf16 pairs: pk2[kb32][pj] = keys (4l5+8m+2t, +1) */     \
        u32 pk2[2][8];                                                           \
        float rs = 0.f;                                                          \
        _Pragma("unroll")                                                        \
        for (int kb32 = 0; kb32 < 2; ++kb32) {                                   \
            _Pragma("unroll")                                                    \
            for (int pj = 0; pj < 8; ++pj) {                                     \
                const int r0 = 4*(pj>>1) + 2*(pj&1);                             \
                const float p0 = __builtin_amdgcn_exp2f(sacc[kb32][r0]);         \
                const float p1 = __builtin_amdgcn_exp2f(sacc[kb32][r0+1]);       \
                rs += p0 + p1;                                                   \
                pk2[kb32][pj] = (u32)f2bf(p0) | ((u32)f2bf(p1) << 16);           \
            }                                                                    \
        }                                                                        \
        psum += rs;                                                              \
        /* PV: per 16-key slice, pre-select + shfl_xor(32); 32x32x16 MFMAs */    \
        __builtin_amdgcn_s_setprio(1);                                           \
        _Pragma("unroll")                                                        \
        for (int kop = 0; kop < 4; ++kop) {                                      \
            const int kb = kop >> 1;                                             \
            const int k2 = (kop & 1) * 4;                                        \
            const u32 s0 = l5 ? pk2[kb][k2+0] : pk2[kb][k2+2];                   \
            const u32 s1 = l5 ? pk2[kb][k2+1] : pk2[kb][k2+3];                   \
            const u32 f0 = __shfl_xor(s0, 32);                                   \
            const u32 f1 = __shfl_xor(s1, 32);                                   \
            u32x4 pw;                                                            \
            pw[0] = l5 ? f0 : pk2[kb][k2+0];                                     \
            pw[1] = l5 ? f1 : pk2[kb][k2+1];                                     \
            pw[2] = l5 ? pk2[kb][k2+2] : f0;                                     \
            pw[3] = l5 ? pk2[kb][k2+3] : f1;                                     \
            s16x8 paf;                                                           \
            __builtin_memcpy(&paf, &pw, 16);                                     \
            _Pragma("unroll")                                                    \
            for (int ndblk = 0; ndblk < 2; ++ndblk) {                            \
                const int rowV = ndblk*32 + l31;                                 \
                const int gV   = 2*kop + l5;                                     \
                s16x8 vf = *(const s16x8*)(vsb + rowV*128                        \
                                           + ((gV ^ SWZ(rowV)) << 4));           \
                oacc[ndblk] = mfma32(paf, vf, oacc[ndblk]);                      \
            }                                                                    \
        }                                                                        \
        __builtin_amdgcn_s_setprio(0);                                           \
    } while (0)

    // prologue: stage round 0 (keys 0..127) into dbuf 0
    STAGE(0, 0);
    asm volatile("s_waitcnt vmcnt(0)" ::: "memory");
    __builtin_amdgcn_s_barrier();

    // 2-phase pipeline over 16 rounds of 128 keys; one vmcnt+barrier per round
    for (int kb2 = 0; kb2 < SEQ/128; kb2 += 2) {
        STAGE(1, kb2 + 1);
        COMPUTE(0, 0);
        COMPUTE(0, 1);
        asm volatile("s_waitcnt vmcnt(0)" ::: "memory");
        __builtin_amdgcn_s_barrier();
        if (kb2 + 2 < SEQ/128) STAGE(0, kb2 + 2);
        COMPUTE(1, 0);
        COMPUTE(1, 1);
        asm volatile("s_waitcnt vmcnt(0)" ::: "memory");
        __builtin_amdgcn_s_barrier();
    }

#undef STAGE
#undef COMPUTE

    // ---- final: psum held per q=l31 (half the keys per lane half); combine
    // halves, invert once, redistribute to the 16 q-rows each lane writes.
    const float pt = psum + __shfl_xor(psum, 32);
    const float rinv_own = 1.0f / pt;            // valid for q = l31
    float* op = out + qkoff;
    #pragma unroll
    for (int r = 0; r < 16; ++r) {
        const int qrow = (r & 3) + 8*(r >> 2) + 4*l5;
        const float ri = __shfl(rinv_own, qrow);
        const size_t q = (size_t)(q0 + w*32 + qrow);
        op[q*DH + l31]      = oacc[0][r] * ri;
        op[q*DH + 32 + l31] = oacc[1][r] * ri;
    }
}

// ---------------------------------------------------------------- launch
extern "C" void kernel_launch(void* const* d_in, const int* in_sizes, int n_in,
                              void* d_out, int out_size, void* d_ws, size_t ws_size,
                              hipStream_t stream)
{
    const float* x    = (const float*)d_in[0];
    const float* W    = (const float*)d_in[1];
    const float* bias = (const float*)d_in[2];
    float* out = (float*)d_out;

    u16* xb = (u16*)d_ws;
    u16* Wt = xb + (size_t)NROW * DMODEL;
    u16* Qb = Wt + (size_t)N3 * DMODEL;
    u16* Kb = Qb + (size_t)BATCH*NH*SEQ*DH;
    u16* Vt = Kb + (size_t)BATCH*NH*SEQ*DH;

    cast_fused_kernel<<<4096 + 768, 256, 0, stream>>>(x, xb, W, Wt);
    qkv_mfma_kernel<<<dim3(N3/128, NROW/128), 256, 0, stream>>>(xb, Wt, bias, Qb, Kb, Vt);
    attn_mfma_kernel<<<dim3(BATCH*NH, SEQ/256), 512, 0, stream>>>(Qb, Kb, Vt, out);
}

// Round 29
// 168.481 us; speedup vs baseline: 1.0363x; 1.0363x over previous
//
#include <hip/hip_runtime.h>
#include <hip/hip_bf16.h>
#include <stdint.h>

typedef float          f32x4  __attribute__((ext_vector_type(4)));
typedef float          f32x16 __attribute__((ext_vector_type(16)));
typedef short          s16x8  __attribute__((ext_vector_type(8)));
typedef unsigned short u16;
typedef u16            u16x4 __attribute__((ext_vector_type(4)));
typedef u16            u16x8 __attribute__((ext_vector_type(8)));
typedef unsigned int   u32;
typedef u32            u32x4 __attribute__((ext_vector_type(4)));

#define DMODEL 1024
#define NH     16
#define DH     64
#define SEQ    2048
#define BATCH  4
#define NROW   (BATCH*SEQ)   // 8192
#define N3     (3*DMODEL)    // 3072

#define KEXP 0.1803368801f   // (1/sqrt(64)) * log2(e), folded into Q

__device__ __forceinline__ u16 f2bf(float f) {
    __hip_bfloat16 h = __float2bfloat16(f);   // RNE conversion
    u16 u;
    __builtin_memcpy(&u, &h, 2);
    return u;
}

typedef const __attribute__((address_space(1))) void* gas_t;
typedef __attribute__((address_space(3))) void* las_t;
__device__ __forceinline__ void async16(void* lds, const void* g) {
    __builtin_amdgcn_global_load_lds((gas_t)g, (las_t)lds, 16, 0, 0);
}

__device__ __forceinline__ f32x4 mfma16(s16x8 a, s16x8 b, f32x4 c) {
    return __builtin_amdgcn_mfma_f32_16x16x32_bf16(a, b, c, 0, 0, 0);
}
__device__ __forceinline__ f32x16 mfma32(s16x8 a, s16x8 b, f32x16 c) {
    return __builtin_amdgcn_mfma_f32_32x32x16_bf16(a, b, c, 0, 0, 0);
}

#define SWZ(row) (((row) & 7) ^ ((((row) >> 3) & 3) << 1))

// ---------------------------------------------------------------- fused casts
// blocks [0, 4096): x -> bf16 ; blocks [4096, 4864): W [k][n] -> Wt bf16 [n][k]
__global__ __launch_bounds__(256)
void cast_fused_kernel(const float* __restrict__ xin, u16* __restrict__ xb,
                       const float* __restrict__ W,  u16* __restrict__ Wt)
{
    __shared__ u16 T[64][72];          // used by the W branch only
    const int t = threadIdx.x;
    if (blockIdx.x < 4096) {
        const int i = blockIdx.x * 256 + t;
        const f32x4* p = (const f32x4*)xin;
        f32x4 a = p[2*i], b = p[2*i+1];
        u16x8 o;
        o[0]=f2bf(a[0]); o[1]=f2bf(a[1]); o[2]=f2bf(a[2]); o[3]=f2bf(a[3]);
        o[4]=f2bf(b[0]); o[5]=f2bf(b[1]); o[6]=f2bf(b[2]); o[7]=f2bf(b[3]);
        ((u16x8*)xb)[i] = o;
        return;
    }
    const int bid2 = blockIdx.x - 4096;           // 0..767
    const int n0 = (bid2 % (N3/64)) * 64;
    const int k0 = (bid2 / (N3/64)) * 64;
    {
        const int c4 = t & 15, rr = t >> 4;
        #pragma unroll
        for (int ri = 0; ri < 4; ++ri) {
            const int r = ri*16 + rr;
            f32x4 v = *(const f32x4*)&W[(size_t)(k0 + r) * N3 + n0 + c4*4];
            #pragma unroll
            for (int e = 0; e < 4; ++e) T[r][c4*4+e] = f2bf(v[e]);
        }
    }
    __syncthreads();
    {
        const int nr = t >> 2, kq = t & 3;
        #pragma unroll
        for (int pp = 0; pp < 2; ++pp) {
            const int kb = kq + pp*4;
            u16x8 o;
            #pragma unroll
            for (int e = 0; e < 8; ++e) o[e] = T[kb*8+e][nr];
            *(u16x8*)&Wt[(size_t)(n0 + nr) * DMODEL + k0 + kb*8] = o;
        }
    }
}

// ---------------------------------------------------------------- QKV GEMM (bf16 MFMA)
// C[8192,3072] = xb @ Wt^T + bias; writes Qb (pre-scaled by KEXP) / Kb [b,h,s,d], Vt [b,h,d,s]
// Single-buffer K-loop: staging is already hidden by multi-block wave overlap
// (16KB LDS -> high occupancy); r28's explicit dbuf (32KB) REGRESSED -5us.
__global__ __launch_bounds__(256)
void qkv_mfma_kernel(const u16* __restrict__ xb, const u16* __restrict__ Wt,
                     const float* __restrict__ bias,
                     u16* __restrict__ Qb, u16* __restrict__ Kb, u16* __restrict__ Vt)
{
    __shared__ u16 As[128*32];   // [m][k] linear
    __shared__ u16 Bs[128*32];   // [n][k] linear (B^T)

    const int tid  = threadIdx.x;
    const int lane = tid & 63;
    const int w    = tid >> 6;
    const int wm   = w >> 1, wn = w & 1;
    const int n0   = blockIdx.x * 128;
    const int m0   = blockIdx.y * 128;

    const int srow = w*32 + (lane >> 2);
    const int scol = (lane & 3) * 8;
    u16* ad0 = &As[(w*2+0)*512 + lane*8];
    u16* ad1 = &As[(w*2+1)*512 + lane*8];
    u16* bd0 = &Bs[(w*2+0)*512 + lane*8];
    u16* bd1 = &Bs[(w*2+1)*512 + lane*8];
    const u16* ag0 = &xb[(size_t)(m0 + srow)      * DMODEL + scol];
    const u16* ag1 = &xb[(size_t)(m0 + srow + 16) * DMODEL + scol];
    const u16* bg0 = &Wt[(size_t)(n0 + srow)      * DMODEL + scol];
    const u16* bg1 = &Wt[(size_t)(n0 + srow + 16) * DMODEL + scol];

    f32x4 acc[4][4];
    #pragma unroll
    for (int i = 0; i < 4; ++i)
        #pragma unroll
        for (int j = 0; j < 4; ++j)
            acc[i][j] = (f32x4){0.f, 0.f, 0.f, 0.f};

    for (int k0 = 0; k0 < DMODEL; k0 += 32) {
        async16(ad0, ag0 + k0);
        async16(ad1, ag1 + k0);
        async16(bd0, bg0 + k0);
        async16(bd1, bg1 + k0);
        __syncthreads();
        s16x8 af[4], bf[4];
        #pragma unroll
        for (int mi = 0; mi < 4; ++mi)
            af[mi] = *(const s16x8*)&As[(wm*64 + mi*16 + (lane&15))*32 + (lane>>4)*8];
        #pragma unroll
        for (int ni = 0; ni < 4; ++ni)
            bf[ni] = *(const s16x8*)&Bs[(wn*64 + ni*16 + (lane&15))*32 + (lane>>4)*8];
        #pragma unroll
        for (int mi = 0; mi < 4; ++mi)
            #pragma unroll
            for (int ni = 0; ni < 4; ++ni)
                acc[mi][ni] = mfma16(af[mi], bf[ni], acc[mi][ni]);
        __syncthreads();
    }

    const int part  = n0 >> 10;                // 0=Q 1=K 2=V
    const int col_l = lane & 15;
    const int h     = ((n0 & 1023) >> 6) + wn;
    float bv[4];
    #pragma unroll
    for (int ni = 0; ni < 4; ++ni) bv[ni] = bias[n0 + wn*64 + ni*16 + col_l];

    const int rbase = m0 + wm*64 + (lane>>4)*4;
    u16* qk = (part == 0) ? Qb : Kb;
    #pragma unroll
    for (int mi = 0; mi < 4; ++mi) {
        const int r0 = rbase + mi*16;
        const int b  = r0 >> 11;
        const int s  = r0 & 2047;
        #pragma unroll
        for (int ni = 0; ni < 4; ++ni) {
            const int d = ni*16 + col_l;
            if (part < 2) {
                u16* base = &qk[(((size_t)b*NH + h)*SEQ + s)*DH + d];
                #pragma unroll
                for (int j = 0; j < 4; ++j) {
                    float v = acc[mi][ni][j] + bv[ni];
                    if (part == 0) v *= KEXP;      // fold softmax scale into Q
                    base[(size_t)j*DH] = f2bf(v);
                }
            } else {
                u16x4 o;
                #pragma unroll
                for (int j = 0; j < 4; ++j) o[j] = f2bf(acc[mi][ni][j] + bv[ni]);
                *(u16x4*)&Vt[(((size_t)b*NH + h)*DH + d)*SEQ + s] = o;
            }
        }
    }
}

// ---------------------------------------------------------------- attention (bf16 MFMA, 32x32)
// r19-proven geometry (102.8us, VGPR=88-96): block = (b,h) x 256-query tile;
// 8 waves x 32 q-rows; grid = (bh, qtile) -> XCD = bh%8, per-XCD K/V = 4MB = L2
// (r27: FETCH 139->41MB, verified). 2 blocks/CU. KV round = 128 keys.
// SWAPPED QK^T via 32x32x16; P register-resident. Compute-bound at this
// structure (r27: FETCH -3.4x with zero dur change).
__global__ __launch_bounds__(512)
void attn_mfma_kernel(const u16* __restrict__ Qb, const u16* __restrict__ Kb,
                      const u16* __restrict__ Vt, float* __restrict__ out)
{
    __shared__ u16 Ks[2][2][64*64];   // [dbuf][sub][key][d], swizzled via source
    __shared__ u16 Vs[2][2][64*64];   // [dbuf][sub][d][key], swizzled via source

    const int tid  = threadIdx.x;
    const int lane = tid & 63;
    const int w    = tid >> 6;            // 0..7
    const int bh   = blockIdx.x;          // fast dim -> XCD = bh % 8
    const int q0   = blockIdx.y * 256;
    const size_t qkoff = (size_t)bh * SEQ * DH;

    const int l5  = lane >> 5;       // 0..1
    const int l31 = lane & 31;       // 0..31

    // Q fragments (B-operand): col=q=l31, k = dop*16 + l5*8 + e
    s16x8 qf[4];
    {
        const u16* qp = &Qb[qkoff + (size_t)(q0 + w*32 + l31)*DH];
        #pragma unroll
        for (int dop = 0; dop < 4; ++dop)
            qf[dop] = *(const s16x8*)(qp + dop*16 + l5*8);
    }

    // staging: 512 threads x 16B = 8KB = one 64-key subtile per issue
    const int skey = tid >> 3;            // 0..63 (row within subtile)
    const int sg   = tid & 7;             // granule within 128B row
    const int gsw8 = (sg ^ SWZ(skey)) * 8;
    const int sdo  = tid * 8;             // linear LDS dest (u16 units)
    const u16* kgb = &Kb[qkoff + (size_t)skey * DH + gsw8];
    const u16* vgb = &Vt[((size_t)bh * DH + skey) * SEQ + gsw8];

    f32x16 oacc[2];
    #pragma unroll
    for (int i = 0; i < 16; ++i) { oacc[0][i] = 0.f; oacc[1][i] = 0.f; }
    float psum = 0.f;

#define STAGE(buf, kb2) do {                                          \
        const size_t _o = (size_t)(kb2) * 128;                        \
        async16(&Ks[buf][0][sdo], kgb + (_o     ) * DH);              \
        async16(&Ks[buf][1][sdo], kgb + (_o + 64) * DH);              \
        async16(&Vs[buf][0][sdo], vgb + _o);                          \
        async16(&Vs[buf][1][sdo], vgb + _o + 64);                     \
    } while (0)

#define COMPUTE(buf, sub) do {                                                   \
        const char* ksb = (const char*)Ks[buf][sub];                             \
        const char* vsb = (const char*)Vs[buf][sub];                             \
        f32x16 sacc[2];                                                          \
        _Pragma("unroll")                                                        \
        for (int i = 0; i < 16; ++i) { sacc[0][i] = 0.f; sacc[1][i] = 0.f; }     \
        __builtin_amdgcn_s_setprio(1);                                           \
        _Pragma("unroll")                                                        \
        for (int dop = 0; dop < 4; ++dop) {                                      \
            _Pragma("unroll")                                                    \
            for (int kb32 = 0; kb32 < 2; ++kb32) {                               \
                const int rowK = kb32*32 + l31;                                  \
                const int gK   = 2*dop + l5;                                     \
                s16x8 kf = *(const s16x8*)(ksb + rowK*128                        \
                                           + ((gK ^ SWZ(rowK)) << 4));           \
                sacc[kb32] = mfma32(kf, qf[dop], sacc[kb32]);                    \
            }                                                                    \
        }                                                                        \
        __builtin_amdgcn_s_setprio(0);                                           \
        /* p = 2^s; pack bf16 pairs: pk2[kb32][pj] = keys (4l5+8m+2t, +1) */     \
        u32 pk2[2][8];                                                           \
        float rs = 0.f;                                                          \
        _Pragma("unroll")                                                        \
        for (int kb32 = 0; kb32 < 2; ++kb32) {                                   \
            _Pragma("unroll")                                                    \
            for (int pj = 0; pj < 8; ++pj) {                                     \
                const int r0 = 4*(pj>>1) + 2*(pj&1);                             \
                const float p0 = __builtin_amdgcn_exp2f(sacc[kb32][r0]);         \
                const float p1 = __builtin_amdgcn_exp2f(sacc[kb32][r0+1]);       \
                rs += p0 + p1;                                                   \
                pk2[kb32][pj] = (u32)f2bf(p0) | ((u32)f2bf(p1) << 16);           \
            }                                                                    \
        }                                                                        \
        psum += rs;                                                              \
        /* PV: per 16-key slice, pre-select + shfl_xor(32); 32x32x16 MFMAs */    \
        __builtin_amdgcn_s_setprio(1);                                           \
        _Pragma("unroll")                                                        \
        for (int kop = 0; kop < 4; ++kop) {                                      \
            const int kb = kop >> 1;                                             \
            const int k2 = (kop & 1) * 4;                                        \
            const u32 s0 = l5 ? pk2[kb][k2+0] : pk2[kb][k2+2];                   \
            const u32 s1 = l5 ? pk2[kb][k2+1] : pk2[kb][k2+3];                   \
            const u32 f0 = __shfl_xor(s0, 32);                                   \
            const u32 f1 = __shfl_xor(s1, 32);                                   \
            u32x4 pw;                                                            \
            pw[0] = l5 ? f0 : pk2[kb][k2+0];                                     \
            pw[1] = l5 ? f1 : pk2[kb][k2+1];                                     \
            pw[2] = l5 ? pk2[kb][k2+2] : f0;                                     \
            pw[3] = l5 ? pk2[kb][k2+3] : f1;                                     \
            s16x8 paf;                                                           \
            __builtin_memcpy(&paf, &pw, 16);                                     \
            _Pragma("unroll")                                                    \
            for (int ndblk = 0; ndblk < 2; ++ndblk) {                            \
                const int rowV = ndblk*32 + l31;                                 \
                const int gV   = 2*kop + l5;                                     \
                s16x8 vf = *(const s16x8*)(vsb + rowV*128                        \
                                           + ((gV ^ SWZ(rowV)) << 4));           \
                oacc[ndblk] = mfma32(paf, vf, oacc[ndblk]);                      \
            }                                                                    \
        }                                                                        \
        __builtin_amdgcn_s_setprio(0);                                           \
    } while (0)

    // prologue: stage round 0 (keys 0..127) into dbuf 0
    STAGE(0, 0);
    asm volatile("s_waitcnt vmcnt(0)" ::: "memory");
    __builtin_amdgcn_s_barrier();

    // 2-phase pipeline over 16 rounds of 128 keys; one vmcnt+barrier per round
    for (int kb2 = 0; kb2 < SEQ/128; kb2 += 2) {
        STAGE(1, kb2 + 1);
        COMPUTE(0, 0);
        COMPUTE(0, 1);
        asm volatile("s_waitcnt vmcnt(0)" ::: "memory");
        __builtin_amdgcn_s_barrier();
        if (kb2 + 2 < SEQ/128) STAGE(0, kb2 + 2);
        COMPUTE(1, 0);
        COMPUTE(1, 1);
        asm volatile("s_waitcnt vmcnt(0)" ::: "memory");
        __builtin_amdgcn_s_barrier();
    }

#undef STAGE
#undef COMPUTE

    // ---- final: psum held per q=l31 (half the keys per lane half); combine
    // halves, invert once, redistribute to the 16 q-rows each lane writes.
    const float pt = psum + __shfl_xor(psum, 32);
    const float rinv_own = 1.0f / pt;            // valid for q = l31
    float* op = out + qkoff;
    #pragma unroll
    for (int r = 0; r < 16; ++r) {
        const int qrow = (r & 3) + 8*(r >> 2) + 4*l5;
        const float ri = __shfl(rinv_own, qrow);
        const size_t q = (size_t)(q0 + w*32 + qrow);
        op[q*DH + l31]      = oacc[0][r] * ri;
        op[q*DH + 32 + l31] = oacc[1][r] * ri;
    }
}

// ---------------------------------------------------------------- launch
extern "C" void kernel_launch(void* const* d_in, const int* in_sizes, int n_in,
                              void* d_out, int out_size, void* d_ws, size_t ws_size,
                              hipStream_t stream)
{
    const float* x    = (const float*)d_in[0];
    const float* W    = (const float*)d_in[1];
    const float* bias = (const float*)d_in[2];
    float* out = (float*)d_out;

    u16* xb = (u16*)d_ws;
    u16* Wt = xb + (size_t)NROW * DMODEL;
    u16* Qb = Wt + (size_t)N3 * DMODEL;
    u16* Kb = Qb + (size_t)BATCH*NH*SEQ*DH;
    u16* Vt = Kb + (size_t)BATCH*NH*SEQ*DH;

    cast_fused_kernel<<<4096 + 768, 256, 0, stream>>>(x, xb, W, Wt);
    qkv_mfma_kernel<<<dim3(N3/128, NROW/128), 256, 0, stream>>>(xb, Wt, bias, Qb, Kb, Vt);
    attn_mfma_kernel<<<dim3(BATCH*NH, SEQ/256), 512, 0, stream>>>(Qb, Kb, Vt, out);
}